// Round 1
// baseline (1253.910 us; speedup 1.0000x reference)
//
#include <hip/hip_runtime.h>

typedef unsigned short u16;
typedef short v8s __attribute__((ext_vector_type(8)));
typedef float v4f __attribute__((ext_vector_type(4)));

constexpr int Tn = 8192;   // tokens = B*S
constexpr int Dd = 1024;   // model dim
constexpr int Hh = 2048;   // hidden dim
constexpr int Ee = 8;      // experts

// round-to-nearest-even f32 -> bf16 (inputs finite)
static __device__ __forceinline__ u16 f2bf(float v) {
  unsigned u = __float_as_uint(v);
  unsigned r = (u + 0x7fffu + ((u >> 16) & 1u)) >> 16;
  return (u16)r;
}

__global__ void convert_x_kernel(const float* __restrict__ x, u16* __restrict__ xb) {
  size_t i = ((size_t)blockIdx.x * 256 + threadIdx.x) * 4;
  float4 v = *reinterpret_cast<const float4*>(x + i);
  ushort4 o;
  o.x = f2bf(v.x); o.y = f2bf(v.y); o.z = f2bf(v.z); o.w = f2bf(v.w);
  *reinterpret_cast<ushort4*>(xb + i) = o;
}

// in: fp32 [E][R][C]  ->  out: bf16 [E][C][R]
__global__ void transpose_cvt_kernel(const float* __restrict__ in, u16* __restrict__ out,
                                     int R, int C) {
  __shared__ float tile[32][33];
  int e = blockIdx.z;
  const float* ip = in + (size_t)e * R * C;
  u16* op = out + (size_t)e * R * C;
  int c0 = blockIdx.x * 32, r0 = blockIdx.y * 32;
  int tx = threadIdx.x, ty = threadIdx.y;  // block (32,8)
  for (int i = ty; i < 32; i += 8)
    tile[i][tx] = ip[(size_t)(r0 + i) * C + c0 + tx];
  __syncthreads();
  for (int i = ty; i < 32; i += 8)
    op[(size_t)(c0 + i) * R + r0 + tx] = f2bf(tile[tx][i]);
}

__global__ __launch_bounds__(256) void gating_kernel(
    const float* __restrict__ x, const float* __restrict__ Wg, const float* __restrict__ bg,
    int* __restrict__ topki, float* __restrict__ topkw, int* __restrict__ counts) {
  int lane = threadIdx.x & 63;
  int t = blockIdx.x * 4 + (threadIdx.x >> 6);
  const float* xr = x + (size_t)t * Dd;
  float acc[8] = {0.f, 0.f, 0.f, 0.f, 0.f, 0.f, 0.f, 0.f};
  for (int d0 = 0; d0 < Dd; d0 += 64) {
    float xv = xr[d0 + lane];
    const float4* wr = reinterpret_cast<const float4*>(Wg + (size_t)(d0 + lane) * 8);
    float4 a = wr[0], b = wr[1];
    acc[0] += xv * a.x; acc[1] += xv * a.y; acc[2] += xv * a.z; acc[3] += xv * a.w;
    acc[4] += xv * b.x; acc[5] += xv * b.y; acc[6] += xv * b.z; acc[7] += xv * b.w;
  }
#pragma unroll
  for (int e = 0; e < 8; ++e) {
#pragma unroll
    for (int off = 32; off > 0; off >>= 1) acc[e] += __shfl_xor(acc[e], off, 64);
  }
  if (lane == 0) {
    float l[8];
    float mx = -1e30f;
#pragma unroll
    for (int e = 0; e < 8; ++e) { l[e] = acc[e] + bg[e]; mx = fmaxf(mx, l[e]); }
    int i0 = 0;
#pragma unroll
    for (int e = 1; e < 8; ++e) if (l[e] > l[i0]) i0 = e;
    int i1 = (i0 == 0) ? 1 : 0;
#pragma unroll
    for (int e = 0; e < 8; ++e) if (e != i0 && l[e] > l[i1]) i1 = e;
    float e0 = __expf(l[i0] - mx), e1 = __expf(l[i1] - mx);
    float inv = 1.0f / (e0 + e1);
    topki[2 * t] = i0; topki[2 * t + 1] = i1;
    topkw[2 * t] = e0 * inv; topkw[2 * t + 1] = e1 * inv;
    atomicAdd(&counts[i0], 1);
    atomicAdd(&counts[i1], 1);
  }
}

__global__ void prefix_kernel(const int* __restrict__ counts, int* __restrict__ offs,
                              int* __restrict__ cursor) {
  if (threadIdx.x == 0) {
    int o = 0;
    for (int e = 0; e < 8; ++e) { offs[e] = o; cursor[e] = o; o += counts[e]; }
    offs[8] = o;
  }
}

__global__ void scatter_kernel(const int* __restrict__ topki, const float* __restrict__ topkw,
                               int* cursor, int* __restrict__ rows, float* __restrict__ roww) {
  int t = blockIdx.x * 256 + threadIdx.x;
#pragma unroll
  for (int k = 0; k < 2; ++k) {
    int e = topki[2 * t + k];
    int slot = atomicAdd(&cursor[e], 1);
    rows[slot] = t;
    roww[slot] = topkw[2 * t + k];
  }
}

// GEMM1: h[slot][n] = gelu( x[rows[slot]] @ W1[e] + b1[e] ), tiles 128x128x32
__global__ __launch_bounds__(256, 2) void gemm1_kernel(
    const u16* __restrict__ xb, const u16* __restrict__ w1t, const float* __restrict__ b1,
    const int* __restrict__ offs, const int* __restrict__ rows, u16* __restrict__ hbuf) {
  const int e = blockIdx.z;
  const int base = offs[e];
  const int cnt = offs[e + 1] - base;
  const int m0 = blockIdx.y * 128;
  if (m0 >= cnt) return;
  const int n0 = blockIdx.x * 128;

  __shared__ u16 As[128][40];
  __shared__ u16 Bs[128][40];

  const int tid = threadIdx.x;
  const int lane = tid & 63;
  const int wid = tid >> 6;
  const int wm = (wid >> 1) * 64;
  const int wn = (wid & 1) * 64;
  const int l16 = lane & 15;
  const int quad = lane >> 4;

  const u16* aptr[2];
  const u16* bptr[2];
  int sr[2], sc[2];
#pragma unroll
  for (int tch = 0; tch < 2; ++tch) {
    int c = tid + tch * 256;
    int r = c >> 2, ch = c & 3;
    sr[tch] = r; sc[tch] = ch * 8;
    int rr = (m0 + r < cnt) ? r : 0;
    aptr[tch] = xb + (size_t)rows[base + m0 + rr] * Dd + ch * 8;
    bptr[tch] = w1t + ((size_t)e * Hh + n0 + r) * Dd + ch * 8;
  }

  v4f acc[4][4];
#pragma unroll
  for (int i = 0; i < 4; ++i)
#pragma unroll
    for (int j = 0; j < 4; ++j) acc[i][j] = {0.f, 0.f, 0.f, 0.f};

  uint4 av[2], bv[2];
#pragma unroll
  for (int tch = 0; tch < 2; ++tch) {
    av[tch] = *reinterpret_cast<const uint4*>(aptr[tch]);
    bv[tch] = *reinterpret_cast<const uint4*>(bptr[tch]);
  }

  for (int k0 = 0; k0 < Dd; k0 += 32) {
    __syncthreads();
#pragma unroll
    for (int tch = 0; tch < 2; ++tch) {
      *reinterpret_cast<uint4*>(&As[sr[tch]][sc[tch]]) = av[tch];
      *reinterpret_cast<uint4*>(&Bs[sr[tch]][sc[tch]]) = bv[tch];
    }
    __syncthreads();
    if (k0 + 32 < Dd) {
#pragma unroll
      for (int tch = 0; tch < 2; ++tch) {
        av[tch] = *reinterpret_cast<const uint4*>(aptr[tch] + k0 + 32);
        bv[tch] = *reinterpret_cast<const uint4*>(bptr[tch] + k0 + 32);
      }
    }
    v8s a[4], b[4];
#pragma unroll
    for (int mt = 0; mt < 4; ++mt)
      a[mt] = *reinterpret_cast<const v8s*>(&As[wm + mt * 16 + l16][quad * 8]);
#pragma unroll
    for (int nt = 0; nt < 4; ++nt)
      b[nt] = *reinterpret_cast<const v8s*>(&Bs[wn + nt * 16 + l16][quad * 8]);
#pragma unroll
    for (int mt = 0; mt < 4; ++mt)
#pragma unroll
      for (int nt = 0; nt < 4; ++nt)
        acc[mt][nt] = __builtin_amdgcn_mfma_f32_16x16x32_bf16(a[mt], b[nt], acc[mt][nt], 0, 0, 0);
  }

  float b1v[4];
  int ng[4];
#pragma unroll
  for (int nt = 0; nt < 4; ++nt) {
    ng[nt] = n0 + wn + nt * 16 + l16;
    b1v[nt] = b1[(size_t)e * Hh + ng[nt]];
  }
#pragma unroll
  for (int mt = 0; mt < 4; ++mt) {
#pragma unroll
    for (int i = 0; i < 4; ++i) {
      int m = wm + mt * 16 + quad * 4 + i;
      if (m0 + m < cnt) {
        size_t rowbase = (size_t)(base + m0 + m) * Hh;
#pragma unroll
        for (int nt = 0; nt < 4; ++nt) {
          float v = acc[mt][nt][i] + b1v[nt];
          float g = 0.5f * v * (1.0f + tanhf(0.7978845608028654f * (v + 0.044715f * v * v * v)));
          hbuf[rowbase + ng[nt]] = f2bf(g);
        }
      }
    }
  }
}

// GEMM2: out[t] += w * ( h[slot] @ W2[e] + b2[e] )
__global__ __launch_bounds__(256, 2) void gemm2_kernel(
    const u16* __restrict__ hbuf, const u16* __restrict__ w2t, const float* __restrict__ b2,
    const int* __restrict__ offs, const int* __restrict__ rows, const float* __restrict__ roww,
    float* __restrict__ out) {
  const int e = blockIdx.z;
  const int base = offs[e];
  const int cnt = offs[e + 1] - base;
  const int m0 = blockIdx.y * 128;
  if (m0 >= cnt) return;
  const int n0 = blockIdx.x * 128;

  __shared__ u16 As[128][40];
  __shared__ u16 Bs[128][40];

  const int tid = threadIdx.x;
  const int lane = tid & 63;
  const int wid = tid >> 6;
  const int wm = (wid >> 1) * 64;
  const int wn = (wid & 1) * 64;
  const int l16 = lane & 15;
  const int quad = lane >> 4;

  const u16* aptr[2];
  const u16* bptr[2];
  int sr[2], sc[2];
#pragma unroll
  for (int tch = 0; tch < 2; ++tch) {
    int c = tid + tch * 256;
    int r = c >> 2, ch = c & 3;
    sr[tch] = r; sc[tch] = ch * 8;
    int rr = (m0 + r < cnt) ? r : 0;
    aptr[tch] = hbuf + (size_t)(base + m0 + rr) * Hh + ch * 8;
    bptr[tch] = w2t + ((size_t)e * Dd + n0 + r) * Hh + ch * 8;
  }

  v4f acc[4][4];
#pragma unroll
  for (int i = 0; i < 4; ++i)
#pragma unroll
    for (int j = 0; j < 4; ++j) acc[i][j] = {0.f, 0.f, 0.f, 0.f};

  uint4 av[2], bv[2];
#pragma unroll
  for (int tch = 0; tch < 2; ++tch) {
    av[tch] = *reinterpret_cast<const uint4*>(aptr[tch]);
    bv[tch] = *reinterpret_cast<const uint4*>(bptr[tch]);
  }

  for (int k0 = 0; k0 < Hh; k0 += 32) {
    __syncthreads();
#pragma unroll
    for (int tch = 0; tch < 2; ++tch) {
      *reinterpret_cast<uint4*>(&As[sr[tch]][sc[tch]]) = av[tch];
      *reinterpret_cast<uint4*>(&Bs[sr[tch]][sc[tch]]) = bv[tch];
    }
    __syncthreads();
    if (k0 + 32 < Hh) {
#pragma unroll
      for (int tch = 0; tch < 2; ++tch) {
        av[tch] = *reinterpret_cast<const uint4*>(aptr[tch] + k0 + 32);
        bv[tch] = *reinterpret_cast<const uint4*>(bptr[tch] + k0 + 32);
      }
    }
    v8s a[4], b[4];
#pragma unroll
    for (int mt = 0; mt < 4; ++mt)
      a[mt] = *reinterpret_cast<const v8s*>(&As[wm + mt * 16 + l16][quad * 8]);
#pragma unroll
    for (int nt = 0; nt < 4; ++nt)
      b[nt] = *reinterpret_cast<const v8s*>(&Bs[wn + nt * 16 + l16][quad * 8]);
#pragma unroll
    for (int mt = 0; mt < 4; ++mt)
#pragma unroll
      for (int nt = 0; nt < 4; ++nt)
        acc[mt][nt] = __builtin_amdgcn_mfma_f32_16x16x32_bf16(a[mt], b[nt], acc[mt][nt], 0, 0, 0);
  }

  float b2v[4];
  int ng[4];
#pragma unroll
  for (int nt = 0; nt < 4; ++nt) {
    ng[nt] = n0 + wn + nt * 16 + l16;
    b2v[nt] = b2[(size_t)e * Dd + ng[nt]];
  }
#pragma unroll
  for (int mt = 0; mt < 4; ++mt) {
#pragma unroll
    for (int i = 0; i < 4; ++i) {
      int m = wm + mt * 16 + quad * 4 + i;
      if (m0 + m < cnt) {
        int t = rows[base + m0 + m];
        float w = roww[base + m0 + m];
        float* orow = out + (size_t)t * Dd;
#pragma unroll
        for (int nt = 0; nt < 4; ++nt)
          atomicAdd(orow + ng[nt], w * (acc[mt][nt][i] + b2v[nt]));
      }
    }
  }
}

extern "C" void kernel_launch(void* const* d_in, const int* in_sizes, int n_in,
                              void* d_out, int out_size, void* d_ws, size_t ws_size,
                              hipStream_t stream) {
  const float* x  = (const float*)d_in[0];
  // d_in[1] = top_k scalar (=2), compile-time fixed
  const float* Wg = (const float*)d_in[2];
  const float* bg = (const float*)d_in[3];
  const float* W1 = (const float*)d_in[4];
  const float* b1 = (const float*)d_in[5];
  const float* W2 = (const float*)d_in[6];
  const float* b2 = (const float*)d_in[7];
  float* out = (float*)d_out;

  char* p = (char*)d_ws;
  auto take = [&](size_t bytes) {
    char* q = p;
    p += (bytes + 255) & ~(size_t)255;
    return q;
  };
  int*   counts = (int*)take(32);
  int*   offs   = (int*)take(64);
  int*   cursor = (int*)take(32);
  int*   topki  = (int*)take((size_t)Tn * 2 * sizeof(int));
  float* topkw  = (float*)take((size_t)Tn * 2 * sizeof(float));
  int*   rows   = (int*)take((size_t)Tn * 2 * sizeof(int));
  float* roww   = (float*)take((size_t)Tn * 2 * sizeof(float));
  u16*   xb     = (u16*)take((size_t)Tn * Dd * 2);
  u16*   w1t    = (u16*)take((size_t)Ee * Dd * Hh * 2);
  u16*   w2t    = (u16*)take((size_t)Ee * Dd * Hh * 2);
  u16*   hbuf   = (u16*)take((size_t)Tn * 2 * Hh * 2);

  hipMemsetAsync(counts, 0, 32, stream);
  hipMemsetAsync(out, 0, (size_t)Tn * Dd * sizeof(float), stream);

  convert_x_kernel<<<(Tn * Dd) / 1024, 256, 0, stream>>>(x, xb);
  transpose_cvt_kernel<<<dim3(Hh / 32, Dd / 32, Ee), dim3(32, 8), 0, stream>>>(W1, w1t, Dd, Hh);
  transpose_cvt_kernel<<<dim3(Dd / 32, Hh / 32, Ee), dim3(32, 8), 0, stream>>>(W2, w2t, Hh, Dd);
  gating_kernel<<<Tn / 4, 256, 0, stream>>>(x, Wg, bg, topki, topkw, counts);
  prefix_kernel<<<1, 64, 0, stream>>>(counts, offs, cursor);
  scatter_kernel<<<Tn / 256, 256, 0, stream>>>(topki, topkw, cursor, rows, roww);
  gemm1_kernel<<<dim3(Hh / 128, 64, Ee), 256, 0, stream>>>(xb, w1t, b1, offs, rows, hbuf);
  gemm2_kernel<<<dim3(Dd / 128, 64, Ee), 256, 0, stream>>>(hbuf, w2t, b2, offs, rows, roww, out);
}

// Round 2
// 723.240 us; speedup vs baseline: 1.7337x; 1.7337x over previous
//
#include <hip/hip_runtime.h>

typedef unsigned short u16;
typedef short v8s __attribute__((ext_vector_type(8)));
typedef float v4f __attribute__((ext_vector_type(4)));

constexpr int Tn = 8192;   // tokens = B*S
constexpr int Dd = 1024;   // model dim
constexpr int Hh = 2048;   // hidden dim
constexpr int Ee = 8;      // experts

// round-to-nearest-even f32 -> bf16 (inputs finite)
static __device__ __forceinline__ u16 f2bf(float v) {
  unsigned u = __float_as_uint(v);
  unsigned r = (u + 0x7fffu + ((u >> 16) & 1u)) >> 16;
  return (u16)r;
}

static __device__ __forceinline__ float bf2f(u16 v) {
  return __uint_as_float(((unsigned)v) << 16);
}

// async global -> LDS, 16B per lane; LDS dest = wave-uniform base + lane*16
static __device__ __forceinline__ void gload_lds16(const u16* g, u16* l) {
  __builtin_amdgcn_global_load_lds(
      (const __attribute__((address_space(1))) unsigned int*)g,
      (__attribute__((address_space(3))) unsigned int*)l, 16, 0, 0);
}

__global__ void convert_x_kernel(const float* __restrict__ x, u16* __restrict__ xb) {
  size_t i = ((size_t)blockIdx.x * 256 + threadIdx.x) * 4;
  float4 v = *reinterpret_cast<const float4*>(x + i);
  ushort4 o;
  o.x = f2bf(v.x); o.y = f2bf(v.y); o.z = f2bf(v.z); o.w = f2bf(v.w);
  *reinterpret_cast<ushort4*>(xb + i) = o;
}

// in: fp32 [E][R][C]  ->  out: bf16 [E][C][R]
__global__ void transpose_cvt_kernel(const float* __restrict__ in, u16* __restrict__ out,
                                     int R, int C) {
  __shared__ float tile[32][33];
  int e = blockIdx.z;
  const float* ip = in + (size_t)e * R * C;
  u16* op = out + (size_t)e * R * C;
  int c0 = blockIdx.x * 32, r0 = blockIdx.y * 32;
  int tx = threadIdx.x, ty = threadIdx.y;  // block (32,8)
  for (int i = ty; i < 32; i += 8)
    tile[i][tx] = ip[(size_t)(r0 + i) * C + c0 + tx];
  __syncthreads();
  for (int i = ty; i < 32; i += 8)
    op[(size_t)(c0 + i) * R + r0 + tx] = f2bf(tile[tx][i]);
}

__global__ __launch_bounds__(256) void gating_kernel(
    const float* __restrict__ x, const float* __restrict__ Wg, const float* __restrict__ bg,
    int* __restrict__ topki, float* __restrict__ topkw, int* __restrict__ counts) {
  int lane = threadIdx.x & 63;
  int t = blockIdx.x * 4 + (threadIdx.x >> 6);
  const float* xr = x + (size_t)t * Dd;
  float acc[8] = {0.f, 0.f, 0.f, 0.f, 0.f, 0.f, 0.f, 0.f};
  for (int d0 = 0; d0 < Dd; d0 += 64) {
    float xv = xr[d0 + lane];
    const float4* wr = reinterpret_cast<const float4*>(Wg + (size_t)(d0 + lane) * 8);
    float4 a = wr[0], b = wr[1];
    acc[0] += xv * a.x; acc[1] += xv * a.y; acc[2] += xv * a.z; acc[3] += xv * a.w;
    acc[4] += xv * b.x; acc[5] += xv * b.y; acc[6] += xv * b.z; acc[7] += xv * b.w;
  }
#pragma unroll
  for (int e = 0; e < 8; ++e) {
#pragma unroll
    for (int off = 32; off > 0; off >>= 1) acc[e] += __shfl_xor(acc[e], off, 64);
  }
  if (lane == 0) {
    float l[8];
    float mx = -1e30f;
#pragma unroll
    for (int e = 0; e < 8; ++e) { l[e] = acc[e] + bg[e]; mx = fmaxf(mx, l[e]); }
    int i0 = 0;
#pragma unroll
    for (int e = 1; e < 8; ++e) if (l[e] > l[i0]) i0 = e;
    int i1 = (i0 == 0) ? 1 : 0;
#pragma unroll
    for (int e = 0; e < 8; ++e) if (e != i0 && l[e] > l[i1]) i1 = e;
    float e0 = __expf(l[i0] - mx), e1 = __expf(l[i1] - mx);
    float inv = 1.0f / (e0 + e1);
    topki[2 * t] = i0; topki[2 * t + 1] = i1;
    topkw[2 * t] = e0 * inv; topkw[2 * t + 1] = e1 * inv;
    atomicAdd(&counts[i0], 1);
    atomicAdd(&counts[i1], 1);
  }
}

__global__ void prefix_kernel(const int* __restrict__ counts, int* __restrict__ offs,
                              int* __restrict__ cursor) {
  if (threadIdx.x == 0) {
    int o = 0;
    for (int e = 0; e < 8; ++e) { offs[e] = o; cursor[e] = o; o += counts[e]; }
    offs[8] = o;
  }
}

__global__ void scatter_kernel(const int* __restrict__ topki, const float* __restrict__ topkw,
                               int* cursor, int* __restrict__ rows, float* __restrict__ roww,
                               int* __restrict__ slotmap) {
  int t = blockIdx.x * 256 + threadIdx.x;
#pragma unroll
  for (int k = 0; k < 2; ++k) {
    int e = topki[2 * t + k];
    int slot = atomicAdd(&cursor[e], 1);
    rows[slot] = t;
    roww[slot] = topkw[2 * t + k];
    slotmap[2 * t + k] = slot;
  }
}

// GEMM1: h[slot][n] = gelu( x[rows[slot]] @ W1[e] + b1[e] ), tiles 128x128x32
__global__ __launch_bounds__(256, 2) void gemm1_kernel(
    const u16* __restrict__ xb, const u16* __restrict__ w1t, const float* __restrict__ b1,
    const int* __restrict__ offs, const int* __restrict__ rows, u16* __restrict__ hbuf) {
  const int e = blockIdx.z;
  const int base = offs[e];
  const int cnt = offs[e + 1] - base;
  const int m0 = blockIdx.y * 128;
  if (m0 >= cnt) return;
  const int n0 = blockIdx.x * 128;

  __shared__ u16 As[128 * 32];
  __shared__ u16 Bs[128 * 32];

  const int tid = threadIdx.x;
  const int lane = tid & 63;
  const int wid = tid >> 6;
  const int wm = (wid >> 1) * 64;
  const int wn = (wid & 1) * 64;
  const int l16 = lane & 15;
  const int quad = lane >> 4;

  // staging: chunk = wid*2 + j covers tile rows [16*chunk, 16*chunk+16)
  const u16* aga[2];
  const u16* bga[2];
  u16* alds[2];
  u16* blds[2];
#pragma unroll
  for (int j = 0; j < 2; ++j) {
    int chunk = wid * 2 + j;
    int row = chunk * 16 + (lane >> 2);
    int kcol = (lane & 3) * 8;
    int ar = (m0 + row < cnt) ? (m0 + row) : 0;
    aga[j] = xb + (size_t)rows[base + ar] * Dd + kcol;
    bga[j] = w1t + ((size_t)e * Hh + n0 + row) * Dd + kcol;
    alds[j] = As + chunk * 512;   // 512 u16 = 1024 B per wave-instruction
    blds[j] = Bs + chunk * 512;
  }

  v4f acc[4][4];
#pragma unroll
  for (int i = 0; i < 4; ++i)
#pragma unroll
    for (int j = 0; j < 4; ++j) acc[i][j] = {0.f, 0.f, 0.f, 0.f};

  for (int k0 = 0; k0 < Dd; k0 += 32) {
    __syncthreads();
    gload_lds16(aga[0] + k0, alds[0]);
    gload_lds16(aga[1] + k0, alds[1]);
    gload_lds16(bga[0] + k0, blds[0]);
    gload_lds16(bga[1] + k0, blds[1]);
    __syncthreads();

    v8s a[4], b[4];
#pragma unroll
    for (int mt = 0; mt < 4; ++mt)
      a[mt] = *reinterpret_cast<const v8s*>(&As[(wm + mt * 16 + l16) * 32 + quad * 8]);
#pragma unroll
    for (int nt = 0; nt < 4; ++nt)
      b[nt] = *reinterpret_cast<const v8s*>(&Bs[(wn + nt * 16 + l16) * 32 + quad * 8]);
#pragma unroll
    for (int mt = 0; mt < 4; ++mt)
#pragma unroll
      for (int nt = 0; nt < 4; ++nt)
        acc[mt][nt] = __builtin_amdgcn_mfma_f32_16x16x32_bf16(a[mt], b[nt], acc[mt][nt], 0, 0, 0);
  }

  float b1v[4];
  int ng[4];
#pragma unroll
  for (int nt = 0; nt < 4; ++nt) {
    ng[nt] = n0 + wn + nt * 16 + l16;
    b1v[nt] = b1[(size_t)e * Hh + ng[nt]];
  }
#pragma unroll
  for (int mt = 0; mt < 4; ++mt) {
#pragma unroll
    for (int i = 0; i < 4; ++i) {
      int m = wm + mt * 16 + quad * 4 + i;
      if (m0 + m < cnt) {
        size_t rowbase = (size_t)(base + m0 + m) * Hh;
#pragma unroll
        for (int nt = 0; nt < 4; ++nt) {
          float v = acc[mt][nt][i] + b1v[nt];
          float g = 0.5f * v * (1.0f + tanhf(0.7978845608028654f * (v + 0.044715f * v * v * v)));
          hbuf[rowbase + ng[nt]] = f2bf(g);
        }
      }
    }
  }
}

// GEMM2: ybuf[slot][n] = h[slot] @ W2[e] + b2[e]  (bf16, no atomics)
__global__ __launch_bounds__(256, 2) void gemm2_kernel(
    const u16* __restrict__ hbuf, const u16* __restrict__ w2t, const float* __restrict__ b2,
    const int* __restrict__ offs, u16* __restrict__ ybuf) {
  const int e = blockIdx.z;
  const int base = offs[e];
  const int cnt = offs[e + 1] - base;
  const int m0 = blockIdx.y * 128;
  if (m0 >= cnt) return;
  const int n0 = blockIdx.x * 128;

  __shared__ u16 As[128 * 32];
  __shared__ u16 Bs[128 * 32];

  const int tid = threadIdx.x;
  const int lane = tid & 63;
  const int wid = tid >> 6;
  const int wm = (wid >> 1) * 64;
  const int wn = (wid & 1) * 64;
  const int l16 = lane & 15;
  const int quad = lane >> 4;

  const u16* aga[2];
  const u16* bga[2];
  u16* alds[2];
  u16* blds[2];
#pragma unroll
  for (int j = 0; j < 2; ++j) {
    int chunk = wid * 2 + j;
    int row = chunk * 16 + (lane >> 2);
    int kcol = (lane & 3) * 8;
    int ar = (m0 + row < cnt) ? (m0 + row) : 0;
    aga[j] = hbuf + (size_t)(base + ar) * Hh + kcol;
    bga[j] = w2t + ((size_t)e * Dd + n0 + row) * Hh + kcol;
    alds[j] = As + chunk * 512;
    blds[j] = Bs + chunk * 512;
  }

  v4f acc[4][4];
#pragma unroll
  for (int i = 0; i < 4; ++i)
#pragma unroll
    for (int j = 0; j < 4; ++j) acc[i][j] = {0.f, 0.f, 0.f, 0.f};

  for (int k0 = 0; k0 < Hh; k0 += 32) {
    __syncthreads();
    gload_lds16(aga[0] + k0, alds[0]);
    gload_lds16(aga[1] + k0, alds[1]);
    gload_lds16(bga[0] + k0, blds[0]);
    gload_lds16(bga[1] + k0, blds[1]);
    __syncthreads();

    v8s a[4], b[4];
#pragma unroll
    for (int mt = 0; mt < 4; ++mt)
      a[mt] = *reinterpret_cast<const v8s*>(&As[(wm + mt * 16 + l16) * 32 + quad * 8]);
#pragma unroll
    for (int nt = 0; nt < 4; ++nt)
      b[nt] = *reinterpret_cast<const v8s*>(&Bs[(wn + nt * 16 + l16) * 32 + quad * 8]);
#pragma unroll
    for (int mt = 0; mt < 4; ++mt)
#pragma unroll
      for (int nt = 0; nt < 4; ++nt)
        acc[mt][nt] = __builtin_amdgcn_mfma_f32_16x16x32_bf16(a[mt], b[nt], acc[mt][nt], 0, 0, 0);
  }

  float b2v[4];
  int ng[4];
#pragma unroll
  for (int nt = 0; nt < 4; ++nt) {
    ng[nt] = n0 + wn + nt * 16 + l16;
    b2v[nt] = b2[(size_t)e * Dd + ng[nt]];
  }
#pragma unroll
  for (int mt = 0; mt < 4; ++mt) {
#pragma unroll
    for (int i = 0; i < 4; ++i) {
      int m = wm + mt * 16 + quad * 4 + i;
      if (m0 + m < cnt) {
        size_t rowbase = (size_t)(base + m0 + m) * Dd;
#pragma unroll
        for (int nt = 0; nt < 4; ++nt)
          ybuf[rowbase + ng[nt]] = f2bf(acc[mt][nt][i] + b2v[nt]);
      }
    }
  }
}

// out[t] = w0 * y[slot0] + w1 * y[slot1]
__global__ __launch_bounds__(256) void combine_kernel(
    const u16* __restrict__ ybuf, const int* __restrict__ slotmap,
    const float* __restrict__ topkw, float* __restrict__ out) {
  int idx = blockIdx.x * 256 + threadIdx.x;
  int t = idx >> 7;            // Dd/8 = 128 threads per token
  int d0 = (idx & 127) * 8;
  int s0 = slotmap[2 * t], s1 = slotmap[2 * t + 1];
  float w0 = topkw[2 * t], w1 = topkw[2 * t + 1];
  uint4 ya = *reinterpret_cast<const uint4*>(ybuf + (size_t)s0 * Dd + d0);
  uint4 yb = *reinterpret_cast<const uint4*>(ybuf + (size_t)s1 * Dd + d0);
  float r[8];
  const unsigned* pa = &ya.x;
  const unsigned* pb = &yb.x;
#pragma unroll
  for (int j = 0; j < 4; ++j) {
    unsigned a = pa[j], b = pb[j];
    r[2 * j]     = w0 * bf2f((u16)(a & 0xffff)) + w1 * bf2f((u16)(b & 0xffff));
    r[2 * j + 1] = w0 * bf2f((u16)(a >> 16))    + w1 * bf2f((u16)(b >> 16));
  }
  float4* op = reinterpret_cast<float4*>(out + (size_t)t * Dd + d0);
  op[0] = make_float4(r[0], r[1], r[2], r[3]);
  op[1] = make_float4(r[4], r[5], r[6], r[7]);
}

extern "C" void kernel_launch(void* const* d_in, const int* in_sizes, int n_in,
                              void* d_out, int out_size, void* d_ws, size_t ws_size,
                              hipStream_t stream) {
  const float* x  = (const float*)d_in[0];
  // d_in[1] = top_k scalar (=2), compile-time fixed
  const float* Wg = (const float*)d_in[2];
  const float* bg = (const float*)d_in[3];
  const float* W1 = (const float*)d_in[4];
  const float* b1 = (const float*)d_in[5];
  const float* W2 = (const float*)d_in[6];
  const float* b2 = (const float*)d_in[7];
  float* out = (float*)d_out;

  char* p = (char*)d_ws;
  auto take = [&](size_t bytes) {
    char* q = p;
    p += (bytes + 255) & ~(size_t)255;
    return q;
  };
  int*   counts  = (int*)take(32);
  int*   offs    = (int*)take(64);
  int*   cursor  = (int*)take(32);
  int*   topki   = (int*)take((size_t)Tn * 2 * sizeof(int));
  float* topkw   = (float*)take((size_t)Tn * 2 * sizeof(float));
  int*   rows    = (int*)take((size_t)Tn * 2 * sizeof(int));
  float* roww    = (float*)take((size_t)Tn * 2 * sizeof(float));
  int*   slotmap = (int*)take((size_t)Tn * 2 * sizeof(int));
  u16*   xb      = (u16*)take((size_t)Tn * Dd * 2);
  u16*   w1t     = (u16*)take((size_t)Ee * Dd * Hh * 2);
  u16*   w2t     = (u16*)take((size_t)Ee * Dd * Hh * 2);
  u16*   hbuf    = (u16*)take((size_t)Tn * 2 * Hh * 2);
  u16*   ybuf    = (u16*)take((size_t)Tn * 2 * Dd * 2);

  hipMemsetAsync(counts, 0, 32, stream);

  convert_x_kernel<<<(Tn * Dd) / 1024, 256, 0, stream>>>(x, xb);
  transpose_cvt_kernel<<<dim3(Hh / 32, Dd / 32, Ee), dim3(32, 8), 0, stream>>>(W1, w1t, Dd, Hh);
  transpose_cvt_kernel<<<dim3(Dd / 32, Hh / 32, Ee), dim3(32, 8), 0, stream>>>(W2, w2t, Hh, Dd);
  gating_kernel<<<Tn / 4, 256, 0, stream>>>(x, Wg, bg, topki, topkw, counts);
  prefix_kernel<<<1, 64, 0, stream>>>(counts, offs, cursor);
  scatter_kernel<<<Tn / 256, 256, 0, stream>>>(topki, topkw, cursor, rows, roww, slotmap);
  gemm1_kernel<<<dim3(Hh / 128, 64, Ee), 256, 0, stream>>>(xb, w1t, b1, offs, rows, hbuf);
  gemm2_kernel<<<dim3(Dd / 128, 64, Ee), 256, 0, stream>>>(hbuf, w2t, b2, offs, ybuf);
  combine_kernel<<<(Tn * Dd / 8) / 256, 256, 0, stream>>>(ybuf, slotmap, topkw, out);
}

// Round 3
// 498.702 us; speedup vs baseline: 2.5143x; 1.4502x over previous
//
#include <hip/hip_runtime.h>

typedef unsigned short u16;
typedef short v8s __attribute__((ext_vector_type(8)));
typedef float v4f __attribute__((ext_vector_type(4)));

constexpr int Tn = 8192;   // tokens = B*S
constexpr int Dd = 1024;   // model dim
constexpr int Hh = 2048;   // hidden dim
constexpr int Ee = 8;      // experts
constexpr int NB = 32;     // histogram/scatter blocks

// round-to-nearest-even f32 -> bf16 (inputs finite)
static __device__ __forceinline__ u16 f2bf(float v) {
  unsigned u = __float_as_uint(v);
  unsigned r = (u + 0x7fffu + ((u >> 16) & 1u)) >> 16;
  return (u16)r;
}

static __device__ __forceinline__ float bf2f(u16 v) {
  return __uint_as_float(((unsigned)v) << 16);
}

// async global -> LDS, 16B per lane; LDS dest = wave-uniform base + lane*16
static __device__ __forceinline__ void gload_lds16(const u16* g, u16* l) {
  __builtin_amdgcn_global_load_lds(
      (const __attribute__((address_space(1))) unsigned int*)g,
      (__attribute__((address_space(3))) unsigned int*)l, 16, 0, 0);
}

__global__ void convert_x_kernel(const float* __restrict__ x, u16* __restrict__ xb) {
  size_t i = ((size_t)blockIdx.x * 256 + threadIdx.x) * 4;
  float4 v = *reinterpret_cast<const float4*>(x + i);
  ushort4 o;
  o.x = f2bf(v.x); o.y = f2bf(v.y); o.z = f2bf(v.z); o.w = f2bf(v.w);
  *reinterpret_cast<ushort4*>(xb + i) = o;
}

// in: fp32 [E][R][C]  ->  out: bf16 [E][C][R]
__global__ void transpose_cvt_kernel(const float* __restrict__ in, u16* __restrict__ out,
                                     int R, int C) {
  __shared__ float tile[32][33];
  int e = blockIdx.z;
  const float* ip = in + (size_t)e * R * C;
  u16* op = out + (size_t)e * R * C;
  int c0 = blockIdx.x * 32, r0 = blockIdx.y * 32;
  int tx = threadIdx.x, ty = threadIdx.y;  // block (32,8)
  for (int i = ty; i < 32; i += 8)
    tile[i][tx] = ip[(size_t)(r0 + i) * C + c0 + tx];
  __syncthreads();
  for (int i = ty; i < 32; i += 8)
    op[(size_t)(c0 + i) * R + r0 + tx] = f2bf(tile[tx][i]);
}

// one wave per token; NO global atomics (that was the 200us serializer)
__global__ __launch_bounds__(256) void gating_kernel(
    const float* __restrict__ x, const float* __restrict__ Wg, const float* __restrict__ bg,
    int* __restrict__ topki, float* __restrict__ topkw) {
  int lane = threadIdx.x & 63;
  int t = blockIdx.x * 4 + (threadIdx.x >> 6);
  const float4* xr = reinterpret_cast<const float4*>(x + (size_t)t * Dd);
  float acc[8] = {0.f, 0.f, 0.f, 0.f, 0.f, 0.f, 0.f, 0.f};
#pragma unroll
  for (int it = 0; it < 4; ++it) {
    float4 xv = xr[it * 64 + lane];
    int r = it * 256 + lane * 4;  // first of 4 consecutive D-rows this lane handles
    const float4* wr = reinterpret_cast<const float4*>(Wg + (size_t)r * 8);
    float xs[4] = {xv.x, xv.y, xv.z, xv.w};
#pragma unroll
    for (int q = 0; q < 4; ++q) {
      float4 a = wr[q * 2], b = wr[q * 2 + 1];
      acc[0] += xs[q] * a.x; acc[1] += xs[q] * a.y; acc[2] += xs[q] * a.z; acc[3] += xs[q] * a.w;
      acc[4] += xs[q] * b.x; acc[5] += xs[q] * b.y; acc[6] += xs[q] * b.z; acc[7] += xs[q] * b.w;
    }
  }
#pragma unroll
  for (int e = 0; e < 8; ++e) {
#pragma unroll
    for (int off = 32; off > 0; off >>= 1) acc[e] += __shfl_xor(acc[e], off, 64);
  }
  if (lane == 0) {
    float l[8];
    float mx = -1e30f;
#pragma unroll
    for (int e = 0; e < 8; ++e) { l[e] = acc[e] + bg[e]; mx = fmaxf(mx, l[e]); }
    int i0 = 0;
#pragma unroll
    for (int e = 1; e < 8; ++e) if (l[e] > l[i0]) i0 = e;
    int i1 = (i0 == 0) ? 1 : 0;
#pragma unroll
    for (int e = 0; e < 8; ++e) if (e != i0 && l[e] > l[i1]) i1 = e;
    float e0 = __expf(l[i0] - mx), e1 = __expf(l[i1] - mx);
    float inv = 1.0f / (e0 + e1);
    topki[2 * t] = i0; topki[2 * t + 1] = i1;
    topkw[2 * t] = e0 * inv; topkw[2 * t + 1] = e1 * inv;
  }
}

// per-block expert histogram via LDS atomics; 8 global stores per block
__global__ __launch_bounds__(256) void hist_kernel(const int* __restrict__ topki,
                                                   int* __restrict__ blockcnt) {
  __shared__ int bins[8];
  int tid = threadIdx.x, b = blockIdx.x;
  if (tid < 8) bins[tid] = 0;
  __syncthreads();
  atomicAdd(&bins[topki[b * 512 + tid]], 1);
  atomicAdd(&bins[topki[b * 512 + 256 + tid]], 1);
  __syncthreads();
  if (tid < 8) blockcnt[b * 8 + tid] = bins[tid];
}

__global__ void prefix_kernel(const int* __restrict__ blockcnt, int* __restrict__ offs,
                              int* __restrict__ blockstart) {
  __shared__ int tmp[8][NB];
  __shared__ int tot[8];
  int tid = threadIdx.x;
  if (tid < 8) {
    int s = 0;
    for (int b = 0; b < NB; ++b) { tmp[tid][b] = s; s += blockcnt[b * 8 + tid]; }
    tot[tid] = s;
  }
  __syncthreads();
  if (tid == 0) {
    int o = 0;
    for (int e = 0; e < 8; ++e) { offs[e] = o; o += tot[e]; }
    offs[8] = o;
  }
  __syncthreads();
  if (tid < 8)
    for (int b = 0; b < NB; ++b) blockstart[b * 8 + tid] = offs[tid] + tmp[tid][b];
}

// slot assignment with LDS-local ranks; zero global atomics
__global__ __launch_bounds__(256) void scatter_kernel(
    const int* __restrict__ topki, const int* __restrict__ blockstart,
    int* __restrict__ rows, int* __restrict__ slotmap) {
  __shared__ int lbins[8];
  int tid = threadIdx.x, b = blockIdx.x;
  if (tid < 8) lbins[tid] = blockstart[b * 8 + tid];
  __syncthreads();
#pragma unroll
  for (int j = 0; j < 2; ++j) {
    int idx = b * 512 + j * 256 + tid;
    int e = topki[idx];
    int slot = atomicAdd(&lbins[e], 1);
    rows[slot] = idx >> 1;
    slotmap[idx] = slot;
  }
}

// GEMM1: h[slot][n] = gelu( x[rows[slot]] @ W1[e] + b1[e] ), tiles 128x128x32
__global__ __launch_bounds__(256, 2) void gemm1_kernel(
    const u16* __restrict__ xb, const u16* __restrict__ w1t, const float* __restrict__ b1,
    const int* __restrict__ offs, const int* __restrict__ rows, u16* __restrict__ hbuf) {
  const int e = blockIdx.z;
  const int base = offs[e];
  const int cnt = offs[e + 1] - base;
  const int m0 = blockIdx.y * 128;
  if (m0 >= cnt) return;
  const int n0 = blockIdx.x * 128;

  __shared__ u16 As[128 * 32];
  __shared__ u16 Bs[128 * 32];

  const int tid = threadIdx.x;
  const int lane = tid & 63;
  const int wid = tid >> 6;
  const int wm = (wid >> 1) * 64;
  const int wn = (wid & 1) * 64;
  const int l16 = lane & 15;
  const int quad = lane >> 4;

  // staging: chunk = wid*2 + j covers tile rows [16*chunk, 16*chunk+16)
  const u16* aga[2];
  const u16* bga[2];
  u16* alds[2];
  u16* blds[2];
#pragma unroll
  for (int j = 0; j < 2; ++j) {
    int chunk = wid * 2 + j;
    int row = chunk * 16 + (lane >> 2);
    int kcol = (lane & 3) * 8;
    int ar = (m0 + row < cnt) ? (m0 + row) : 0;
    aga[j] = xb + (size_t)rows[base + ar] * Dd + kcol;
    bga[j] = w1t + ((size_t)e * Hh + n0 + row) * Dd + kcol;
    alds[j] = As + chunk * 512;   // 512 u16 = 1024 B per wave-instruction
    blds[j] = Bs + chunk * 512;
  }

  v4f acc[4][4];
#pragma unroll
  for (int i = 0; i < 4; ++i)
#pragma unroll
    for (int j = 0; j < 4; ++j) acc[i][j] = {0.f, 0.f, 0.f, 0.f};

  for (int k0 = 0; k0 < Dd; k0 += 32) {
    __syncthreads();
    gload_lds16(aga[0] + k0, alds[0]);
    gload_lds16(aga[1] + k0, alds[1]);
    gload_lds16(bga[0] + k0, blds[0]);
    gload_lds16(bga[1] + k0, blds[1]);
    __syncthreads();

    v8s a[4], b[4];
#pragma unroll
    for (int mt = 0; mt < 4; ++mt)
      a[mt] = *reinterpret_cast<const v8s*>(&As[(wm + mt * 16 + l16) * 32 + quad * 8]);
#pragma unroll
    for (int nt = 0; nt < 4; ++nt)
      b[nt] = *reinterpret_cast<const v8s*>(&Bs[(wn + nt * 16 + l16) * 32 + quad * 8]);
#pragma unroll
    for (int mt = 0; mt < 4; ++mt)
#pragma unroll
      for (int nt = 0; nt < 4; ++nt)
        acc[mt][nt] = __builtin_amdgcn_mfma_f32_16x16x32_bf16(a[mt], b[nt], acc[mt][nt], 0, 0, 0);
  }

  float b1v[4];
  int ng[4];
#pragma unroll
  for (int nt = 0; nt < 4; ++nt) {
    ng[nt] = n0 + wn + nt * 16 + l16;
    b1v[nt] = b1[(size_t)e * Hh + ng[nt]];
  }
#pragma unroll
  for (int mt = 0; mt < 4; ++mt) {
#pragma unroll
    for (int i = 0; i < 4; ++i) {
      int m = wm + mt * 16 + quad * 4 + i;
      if (m0 + m < cnt) {
        size_t rowbase = (size_t)(base + m0 + m) * Hh;
#pragma unroll
        for (int nt = 0; nt < 4; ++nt) {
          float v = acc[mt][nt][i] + b1v[nt];
          float g = 0.5f * v * (1.0f + tanhf(0.7978845608028654f * (v + 0.044715f * v * v * v)));
          hbuf[rowbase + ng[nt]] = f2bf(g);
        }
      }
    }
  }
}

// GEMM2: ybuf[slot][n] = h[slot] @ W2[e] + b2[e]  (bf16, no atomics)
__global__ __launch_bounds__(256, 2) void gemm2_kernel(
    const u16* __restrict__ hbuf, const u16* __restrict__ w2t, const float* __restrict__ b2,
    const int* __restrict__ offs, u16* __restrict__ ybuf) {
  const int e = blockIdx.z;
  const int base = offs[e];
  const int cnt = offs[e + 1] - base;
  const int m0 = blockIdx.y * 128;
  if (m0 >= cnt) return;
  const int n0 = blockIdx.x * 128;

  __shared__ u16 As[128 * 32];
  __shared__ u16 Bs[128 * 32];

  const int tid = threadIdx.x;
  const int lane = tid & 63;
  const int wid = tid >> 6;
  const int wm = (wid >> 1) * 64;
  const int wn = (wid & 1) * 64;
  const int l16 = lane & 15;
  const int quad = lane >> 4;

  const u16* aga[2];
  const u16* bga[2];
  u16* alds[2];
  u16* blds[2];
#pragma unroll
  for (int j = 0; j < 2; ++j) {
    int chunk = wid * 2 + j;
    int row = chunk * 16 + (lane >> 2);
    int kcol = (lane & 3) * 8;
    int ar = (m0 + row < cnt) ? (m0 + row) : 0;
    aga[j] = hbuf + (size_t)(base + ar) * Hh + kcol;
    bga[j] = w2t + ((size_t)e * Dd + n0 + row) * Hh + kcol;
    alds[j] = As + chunk * 512;
    blds[j] = Bs + chunk * 512;
  }

  v4f acc[4][4];
#pragma unroll
  for (int i = 0; i < 4; ++i)
#pragma unroll
    for (int j = 0; j < 4; ++j) acc[i][j] = {0.f, 0.f, 0.f, 0.f};

  for (int k0 = 0; k0 < Hh; k0 += 32) {
    __syncthreads();
    gload_lds16(aga[0] + k0, alds[0]);
    gload_lds16(aga[1] + k0, alds[1]);
    gload_lds16(bga[0] + k0, blds[0]);
    gload_lds16(bga[1] + k0, blds[1]);
    __syncthreads();

    v8s a[4], b[4];
#pragma unroll
    for (int mt = 0; mt < 4; ++mt)
      a[mt] = *reinterpret_cast<const v8s*>(&As[(wm + mt * 16 + l16) * 32 + quad * 8]);
#pragma unroll
    for (int nt = 0; nt < 4; ++nt)
      b[nt] = *reinterpret_cast<const v8s*>(&Bs[(wn + nt * 16 + l16) * 32 + quad * 8]);
#pragma unroll
    for (int mt = 0; mt < 4; ++mt)
#pragma unroll
      for (int nt = 0; nt < 4; ++nt)
        acc[mt][nt] = __builtin_amdgcn_mfma_f32_16x16x32_bf16(a[mt], b[nt], acc[mt][nt], 0, 0, 0);
  }

  float b2v[4];
  int ng[4];
#pragma unroll
  for (int nt = 0; nt < 4; ++nt) {
    ng[nt] = n0 + wn + nt * 16 + l16;
    b2v[nt] = b2[(size_t)e * Dd + ng[nt]];
  }
#pragma unroll
  for (int mt = 0; mt < 4; ++mt) {
#pragma unroll
    for (int i = 0; i < 4; ++i) {
      int m = wm + mt * 16 + quad * 4 + i;
      if (m0 + m < cnt) {
        size_t rowbase = (size_t)(base + m0 + m) * Dd;
#pragma unroll
        for (int nt = 0; nt < 4; ++nt)
          ybuf[rowbase + ng[nt]] = f2bf(acc[mt][nt][i] + b2v[nt]);
      }
    }
  }
}

// out[t] = w0 * y[slot0] + w1 * y[slot1]
__global__ __launch_bounds__(256) void combine_kernel(
    const u16* __restrict__ ybuf, const int* __restrict__ slotmap,
    const float* __restrict__ topkw, float* __restrict__ out) {
  int idx = blockIdx.x * 256 + threadIdx.x;
  int t = idx >> 7;            // Dd/8 = 128 threads per token
  int d0 = (idx & 127) * 8;
  int s0 = slotmap[2 * t], s1 = slotmap[2 * t + 1];
  float w0 = topkw[2 * t], w1 = topkw[2 * t + 1];
  uint4 ya = *reinterpret_cast<const uint4*>(ybuf + (size_t)s0 * Dd + d0);
  uint4 yb = *reinterpret_cast<const uint4*>(ybuf + (size_t)s1 * Dd + d0);
  float r[8];
  const unsigned* pa = &ya.x;
  const unsigned* pb = &yb.x;
#pragma unroll
  for (int j = 0; j < 4; ++j) {
    unsigned a = pa[j], b = pb[j];
    r[2 * j]     = w0 * bf2f((u16)(a & 0xffff)) + w1 * bf2f((u16)(b & 0xffff));
    r[2 * j + 1] = w0 * bf2f((u16)(a >> 16))    + w1 * bf2f((u16)(b >> 16));
  }
  float4* op = reinterpret_cast<float4*>(out + (size_t)t * Dd + d0);
  op[0] = make_float4(r[0], r[1], r[2], r[3]);
  op[1] = make_float4(r[4], r[5], r[6], r[7]);
}

extern "C" void kernel_launch(void* const* d_in, const int* in_sizes, int n_in,
                              void* d_out, int out_size, void* d_ws, size_t ws_size,
                              hipStream_t stream) {
  const float* x  = (const float*)d_in[0];
  // d_in[1] = top_k scalar (=2), compile-time fixed
  const float* Wg = (const float*)d_in[2];
  const float* bg = (const float*)d_in[3];
  const float* W1 = (const float*)d_in[4];
  const float* b1 = (const float*)d_in[5];
  const float* W2 = (const float*)d_in[6];
  const float* b2 = (const float*)d_in[7];
  float* out = (float*)d_out;

  char* p = (char*)d_ws;
  auto take = [&](size_t bytes) {
    char* q = p;
    p += (bytes + 255) & ~(size_t)255;
    return q;
  };
  int*   offs       = (int*)take(64);
  int*   blockcnt   = (int*)take((size_t)NB * 8 * sizeof(int));
  int*   blockstart = (int*)take((size_t)NB * 8 * sizeof(int));
  int*   topki      = (int*)take((size_t)Tn * 2 * sizeof(int));
  float* topkw      = (float*)take((size_t)Tn * 2 * sizeof(float));
  int*   rows       = (int*)take((size_t)Tn * 2 * sizeof(int));
  int*   slotmap    = (int*)take((size_t)Tn * 2 * sizeof(int));
  u16*   xb         = (u16*)take((size_t)Tn * Dd * 2);
  u16*   w1t        = (u16*)take((size_t)Ee * Dd * Hh * 2);
  u16*   w2t        = (u16*)take((size_t)Ee * Dd * Hh * 2);
  u16*   hbuf       = (u16*)take((size_t)Tn * 2 * Hh * 2);
  u16*   ybuf       = (u16*)take((size_t)Tn * 2 * Dd * 2);

  convert_x_kernel<<<(Tn * Dd) / 1024, 256, 0, stream>>>(x, xb);
  transpose_cvt_kernel<<<dim3(Hh / 32, Dd / 32, Ee), dim3(32, 8), 0, stream>>>(W1, w1t, Dd, Hh);
  transpose_cvt_kernel<<<dim3(Dd / 32, Hh / 32, Ee), dim3(32, 8), 0, stream>>>(W2, w2t, Hh, Dd);
  gating_kernel<<<Tn / 4, 256, 0, stream>>>(x, Wg, bg, topki, topkw);
  hist_kernel<<<NB, 256, 0, stream>>>(topki, blockcnt);
  prefix_kernel<<<1, 64, 0, stream>>>(blockcnt, offs, blockstart);
  scatter_kernel<<<NB, 256, 0, stream>>>(topki, blockstart, rows, slotmap);
  gemm1_kernel<<<dim3(Hh / 128, 64, Ee), 256, 0, stream>>>(xb, w1t, b1, offs, rows, hbuf);
  gemm2_kernel<<<dim3(Dd / 128, 64, Ee), 256, 0, stream>>>(hbuf, w2t, b2, offs, ybuf);
  combine_kernel<<<(Tn * Dd / 8) / 256, 256, 0, stream>>>(ybuf, slotmap, topkw, out);
}

// Round 4
// 475.199 us; speedup vs baseline: 2.6387x; 1.0495x over previous
//
#include <hip/hip_runtime.h>

typedef unsigned short u16;
typedef short v8s __attribute__((ext_vector_type(8)));
typedef float v4f __attribute__((ext_vector_type(4)));

constexpr int Tn = 8192;   // tokens = B*S
constexpr int Dd = 1024;   // model dim
constexpr int Hh = 2048;   // hidden dim
constexpr int Ee = 8;      // experts
constexpr int NB = 32;     // histogram/scatter blocks
constexpr int MAXP = 17;   // ceil(max panels / 8) ; panels <= 128+8=136

// round-to-nearest-even f32 -> bf16 (inputs finite)
static __device__ __forceinline__ u16 f2bf(float v) {
  unsigned u = __float_as_uint(v);
  unsigned r = (u + 0x7fffu + ((u >> 16) & 1u)) >> 16;
  return (u16)r;
}

static __device__ __forceinline__ float bf2f(u16 v) {
  return __uint_as_float(((unsigned)v) << 16);
}

// async global -> LDS, 16B per lane; LDS dest = wave-uniform base + lane*16
static __device__ __forceinline__ void gload_lds16(const u16* g, u16* l) {
  __builtin_amdgcn_global_load_lds(
      (const __attribute__((address_space(1))) unsigned int*)g,
      (__attribute__((address_space(3))) unsigned int*)l, 16, 0, 0);
}

// in: fp32 [E][R][C]  ->  out: bf16 [E][C][R], 64x64 tiles
__global__ __launch_bounds__(512) void transpose_cvt_kernel(
    const float* __restrict__ in, u16* __restrict__ out, int R, int C) {
  __shared__ float tile[64][65];
  int e = blockIdx.z;
  const float* ip = in + (size_t)e * R * C;
  u16* op = out + (size_t)e * R * C;
  int c0 = blockIdx.x * 64, r0 = blockIdx.y * 64;
  int tx = threadIdx.x, ty = threadIdx.y;  // block (64,8)
  for (int i = ty; i < 64; i += 8)
    tile[i][tx] = ip[(size_t)(r0 + i) * C + c0 + tx];
  __syncthreads();
  for (int i = ty; i < 64; i += 8)
    op[(size_t)(c0 + i) * R + r0 + tx] = f2bf(tile[tx][i]);
}

// one wave per token; fused x->bf16 conversion; no global atomics
__global__ __launch_bounds__(256) void gating_kernel(
    const float* __restrict__ x, const float* __restrict__ Wg, const float* __restrict__ bg,
    int* __restrict__ topki, float* __restrict__ topkw, u16* __restrict__ xb) {
  int lane = threadIdx.x & 63;
  int t = blockIdx.x * 4 + (threadIdx.x >> 6);
  const float4* xr = reinterpret_cast<const float4*>(x + (size_t)t * Dd);
  float acc[8] = {0.f, 0.f, 0.f, 0.f, 0.f, 0.f, 0.f, 0.f};
#pragma unroll
  for (int it = 0; it < 4; ++it) {
    float4 xv = xr[it * 64 + lane];
    int r = it * 256 + lane * 4;  // first of 4 consecutive D-rows this lane handles
    // fused bf16 conversion of x
    ushort4 o;
    o.x = f2bf(xv.x); o.y = f2bf(xv.y); o.z = f2bf(xv.z); o.w = f2bf(xv.w);
    *reinterpret_cast<ushort4*>(xb + (size_t)t * Dd + r) = o;
    const float4* wr = reinterpret_cast<const float4*>(Wg + (size_t)r * 8);
    float xs[4] = {xv.x, xv.y, xv.z, xv.w};
#pragma unroll
    for (int q = 0; q < 4; ++q) {
      float4 a = wr[q * 2], b = wr[q * 2 + 1];
      acc[0] += xs[q] * a.x; acc[1] += xs[q] * a.y; acc[2] += xs[q] * a.z; acc[3] += xs[q] * a.w;
      acc[4] += xs[q] * b.x; acc[5] += xs[q] * b.y; acc[6] += xs[q] * b.z; acc[7] += xs[q] * b.w;
    }
  }
#pragma unroll
  for (int e = 0; e < 8; ++e) {
#pragma unroll
    for (int off = 32; off > 0; off >>= 1) acc[e] += __shfl_xor(acc[e], off, 64);
  }
  if (lane == 0) {
    float l[8];
    float mx = -1e30f;
#pragma unroll
    for (int e = 0; e < 8; ++e) { l[e] = acc[e] + bg[e]; mx = fmaxf(mx, l[e]); }
    int i0 = 0;
#pragma unroll
    for (int e = 1; e < 8; ++e) if (l[e] > l[i0]) i0 = e;
    int i1 = (i0 == 0) ? 1 : 0;
#pragma unroll
    for (int e = 0; e < 8; ++e) if (e != i0 && l[e] > l[i1]) i1 = e;
    float e0 = __expf(l[i0] - mx), e1 = __expf(l[i1] - mx);
    float inv = 1.0f / (e0 + e1);
    topki[2 * t] = i0; topki[2 * t + 1] = i1;
    topkw[2 * t] = e0 * inv; topkw[2 * t + 1] = e1 * inv;
  }
}

// per-block expert histogram via LDS atomics; 8 global stores per block
__global__ __launch_bounds__(256) void hist_kernel(const int* __restrict__ topki,
                                                   int* __restrict__ blockcnt) {
  __shared__ int bins[8];
  int tid = threadIdx.x, b = blockIdx.x;
  if (tid < 8) bins[tid] = 0;
  __syncthreads();
  atomicAdd(&bins[topki[b * 512 + tid]], 1);
  atomicAdd(&bins[topki[b * 512 + 256 + tid]], 1);
  __syncthreads();
  if (tid < 8) blockcnt[b * 8 + tid] = bins[tid];
}

// prefix sums + XCD-pinned panel work-list
__global__ void prefix_kernel(const int* __restrict__ blockcnt, int* __restrict__ offs,
                              int* __restrict__ blockstart,
                              int* __restrict__ panelE, int* __restrict__ panelB,
                              int* __restrict__ nPanels) {
  __shared__ int tmp[8][NB];
  __shared__ int tot[8];
  int tid = threadIdx.x;
  if (tid < 8) {
    int s = 0;
    for (int b = 0; b < NB; ++b) { tmp[tid][b] = s; s += blockcnt[b * 8 + tid]; }
    tot[tid] = s;
  }
  __syncthreads();
  if (tid == 0) {
    int o = 0;
    for (int e = 0; e < 8; ++e) { offs[e] = o; o += tot[e]; }
    offs[8] = o;
    // panel list: one entry per 128-row m-tile, expert-major
    int np = 0;
    for (int e = 0; e < 8; ++e) {
      for (int m0 = 0; m0 < tot[e]; m0 += 128) {
        panelE[np] = e;
        panelB[np] = offs[e] + m0;
        ++np;
      }
    }
    *nPanels = np;
  }
  __syncthreads();
  if (tid < 8)
    for (int b = 0; b < NB; ++b) blockstart[b * 8 + tid] = offs[tid] + tmp[tid][b];
}

// slot assignment with LDS-local ranks; zero global atomics
__global__ __launch_bounds__(256) void scatter_kernel(
    const int* __restrict__ topki, const int* __restrict__ blockstart,
    int* __restrict__ rows, int* __restrict__ slotmap) {
  __shared__ int lbins[8];
  int tid = threadIdx.x, b = blockIdx.x;
  if (tid < 8) lbins[tid] = blockstart[b * 8 + tid];
  __syncthreads();
#pragma unroll
  for (int j = 0; j < 2; ++j) {
    int idx = b * 512 + j * 256 + tid;
    int e = topki[idx];
    int slot = atomicAdd(&lbins[e], 1);
    rows[slot] = idx >> 1;
    slotmap[idx] = slot;
  }
}

// GEMM1: h[slot][n] = gelu( x[rows[slot]] @ W1[e] + b1[e] )
// 1-D grid, XCD-pinned panels: xcd=bid&7 keeps one A-panel in its L2 across all 16 n-blocks
__global__ __launch_bounds__(256, 2) void gemm1_kernel(
    const u16* __restrict__ xb, const u16* __restrict__ w1t, const float* __restrict__ b1,
    const int* __restrict__ offs, const int* __restrict__ rows,
    const int* __restrict__ panelE, const int* __restrict__ panelB,
    const int* __restrict__ nPanels, u16* __restrict__ hbuf) {
  const int bid = blockIdx.x;
  const int xcd = bid & 7;
  const int q = bid >> 3;
  const int n = q & 15;               // Hh/128 = 16 n-blocks
  const int pi = (q >> 4) * 8 + xcd;
  if (pi >= *nPanels) return;
  const int e = panelE[pi];
  const int sbase = panelB[pi];       // global slot row of panel start
  const int lim = offs[e + 1];
  const int n0 = n * 128;

  __shared__ u16 As[128 * 32];
  __shared__ u16 Bs[128 * 32];

  const int tid = threadIdx.x;
  const int lane = tid & 63;
  const int wid = tid >> 6;
  const int wm = (wid >> 1) * 64;
  const int wn = (wid & 1) * 64;
  const int l16 = lane & 15;
  const int quad = lane >> 4;

  const u16* aga[2];
  const u16* bga[2];
  u16* alds[2];
  u16* blds[2];
#pragma unroll
  for (int j = 0; j < 2; ++j) {
    int chunk = wid * 2 + j;
    int row = chunk * 16 + (lane >> 2);
    int kcol = (lane & 3) * 8;
    int slot = sbase + row;
    if (slot >= lim) slot = sbase;
    aga[j] = xb + (size_t)rows[slot] * Dd + kcol;
    bga[j] = w1t + ((size_t)e * Hh + n0 + row) * Dd + kcol;
    alds[j] = As + chunk * 512;
    blds[j] = Bs + chunk * 512;
  }

  v4f acc[4][4];
#pragma unroll
  for (int i = 0; i < 4; ++i)
#pragma unroll
    for (int j = 0; j < 4; ++j) acc[i][j] = {0.f, 0.f, 0.f, 0.f};

  for (int k0 = 0; k0 < Dd; k0 += 32) {
    __syncthreads();
    gload_lds16(aga[0] + k0, alds[0]);
    gload_lds16(aga[1] + k0, alds[1]);
    gload_lds16(bga[0] + k0, blds[0]);
    gload_lds16(bga[1] + k0, blds[1]);
    __syncthreads();

    v8s a[4], b[4];
#pragma unroll
    for (int mt = 0; mt < 4; ++mt)
      a[mt] = *reinterpret_cast<const v8s*>(&As[(wm + mt * 16 + l16) * 32 + quad * 8]);
#pragma unroll
    for (int nt = 0; nt < 4; ++nt)
      b[nt] = *reinterpret_cast<const v8s*>(&Bs[(wn + nt * 16 + l16) * 32 + quad * 8]);
#pragma unroll
    for (int mt = 0; mt < 4; ++mt)
#pragma unroll
      for (int nt = 0; nt < 4; ++nt)
        acc[mt][nt] = __builtin_amdgcn_mfma_f32_16x16x32_bf16(a[mt], b[nt], acc[mt][nt], 0, 0, 0);
  }

  float b1v[4];
  int ng[4];
#pragma unroll
  for (int nt = 0; nt < 4; ++nt) {
    ng[nt] = n0 + wn + nt * 16 + l16;
    b1v[nt] = b1[(size_t)e * Hh + ng[nt]];
  }
#pragma unroll
  for (int mt = 0; mt < 4; ++mt) {
#pragma unroll
    for (int i = 0; i < 4; ++i) {
      int m = wm + mt * 16 + quad * 4 + i;
      if (sbase + m < lim) {
        size_t rowbase = (size_t)(sbase + m) * Hh;
#pragma unroll
        for (int nt = 0; nt < 4; ++nt) {
          float v = acc[mt][nt][i] + b1v[nt];
          // gelu(tanh approx) = v * sigmoid(2*0.79788456*(v + 0.044715 v^3))
          float s = 1.0f / (1.0f + __expf(-1.5957691216057308f * (v + 0.044715f * v * v * v)));
          hbuf[rowbase + ng[nt]] = f2bf(v * s);
        }
      }
    }
  }
}

// GEMM2: ybuf[slot][n] = h[slot] @ W2[e] + b2[e]
__global__ __launch_bounds__(256, 2) void gemm2_kernel(
    const u16* __restrict__ hbuf, const u16* __restrict__ w2t, const float* __restrict__ b2,
    const int* __restrict__ offs,
    const int* __restrict__ panelE, const int* __restrict__ panelB,
    const int* __restrict__ nPanels, u16* __restrict__ ybuf) {
  const int bid = blockIdx.x;
  const int xcd = bid & 7;
  const int q = bid >> 3;
  const int n = q & 7;                // Dd/128 = 8 n-blocks
  const int pi = (q >> 3) * 8 + xcd;
  if (pi >= *nPanels) return;
  const int e = panelE[pi];
  const int sbase = panelB[pi];
  const int lim = offs[e + 1];
  const int n0 = n * 128;

  __shared__ u16 As[128 * 32];
  __shared__ u16 Bs[128 * 32];

  const int tid = threadIdx.x;
  const int lane = tid & 63;
  const int wid = tid >> 6;
  const int wm = (wid >> 1) * 64;
  const int wn = (wid & 1) * 64;
  const int l16 = lane & 15;
  const int quad = lane >> 4;

  const u16* aga[2];
  const u16* bga[2];
  u16* alds[2];
  u16* blds[2];
#pragma unroll
  for (int j = 0; j < 2; ++j) {
    int chunk = wid * 2 + j;
    int row = chunk * 16 + (lane >> 2);
    int kcol = (lane & 3) * 8;
    int slot = sbase + row;
    if (slot >= lim) slot = sbase;
    aga[j] = hbuf + (size_t)slot * Hh + kcol;
    bga[j] = w2t + ((size_t)e * Dd + n0 + row) * Hh + kcol;
    alds[j] = As + chunk * 512;
    blds[j] = Bs + chunk * 512;
  }

  v4f acc[4][4];
#pragma unroll
  for (int i = 0; i < 4; ++i)
#pragma unroll
    for (int j = 0; j < 4; ++j) acc[i][j] = {0.f, 0.f, 0.f, 0.f};

  for (int k0 = 0; k0 < Hh; k0 += 32) {
    __syncthreads();
    gload_lds16(aga[0] + k0, alds[0]);
    gload_lds16(aga[1] + k0, alds[1]);
    gload_lds16(bga[0] + k0, blds[0]);
    gload_lds16(bga[1] + k0, blds[1]);
    __syncthreads();

    v8s a[4], b[4];
#pragma unroll
    for (int mt = 0; mt < 4; ++mt)
      a[mt] = *reinterpret_cast<const v8s*>(&As[(wm + mt * 16 + l16) * 32 + quad * 8]);
#pragma unroll
    for (int nt = 0; nt < 4; ++nt)
      b[nt] = *reinterpret_cast<const v8s*>(&Bs[(wn + nt * 16 + l16) * 32 + quad * 8]);
#pragma unroll
    for (int mt = 0; mt < 4; ++mt)
#pragma unroll
      for (int nt = 0; nt < 4; ++nt)
        acc[mt][nt] = __builtin_amdgcn_mfma_f32_16x16x32_bf16(a[mt], b[nt], acc[mt][nt], 0, 0, 0);
  }

  float b2v[4];
  int ng[4];
#pragma unroll
  for (int nt = 0; nt < 4; ++nt) {
    ng[nt] = n0 + wn + nt * 16 + l16;
    b2v[nt] = b2[(size_t)e * Dd + ng[nt]];
  }
#pragma unroll
  for (int mt = 0; mt < 4; ++mt) {
#pragma unroll
    for (int i = 0; i < 4; ++i) {
      int m = wm + mt * 16 + quad * 4 + i;
      if (sbase + m < lim) {
        size_t rowbase = (size_t)(sbase + m) * Dd;
#pragma unroll
        for (int nt = 0; nt < 4; ++nt)
          ybuf[rowbase + ng[nt]] = f2bf(acc[mt][nt][i] + b2v[nt]);
      }
    }
  }
}

// out[t] = w0 * y[slot0] + w1 * y[slot1]
__global__ __launch_bounds__(256) void combine_kernel(
    const u16* __restrict__ ybuf, const int* __restrict__ slotmap,
    const float* __restrict__ topkw, float* __restrict__ out) {
  int idx = blockIdx.x * 256 + threadIdx.x;
  int t = idx >> 7;            // Dd/8 = 128 threads per token
  int d0 = (idx & 127) * 8;
  int s0 = slotmap[2 * t], s1 = slotmap[2 * t + 1];
  float w0 = topkw[2 * t], w1 = topkw[2 * t + 1];
  uint4 ya = *reinterpret_cast<const uint4*>(ybuf + (size_t)s0 * Dd + d0);
  uint4 yb = *reinterpret_cast<const uint4*>(ybuf + (size_t)s1 * Dd + d0);
  float r[8];
  const unsigned* pa = &ya.x;
  const unsigned* pb = &yb.x;
#pragma unroll
  for (int j = 0; j < 4; ++j) {
    unsigned a = pa[j], b = pb[j];
    r[2 * j]     = w0 * bf2f((u16)(a & 0xffff)) + w1 * bf2f((u16)(b & 0xffff));
    r[2 * j + 1] = w0 * bf2f((u16)(a >> 16))    + w1 * bf2f((u16)(b >> 16));
  }
  float4* op = reinterpret_cast<float4*>(out + (size_t)t * Dd + d0);
  op[0] = make_float4(r[0], r[1], r[2], r[3]);
  op[1] = make_float4(r[4], r[5], r[6], r[7]);
}

extern "C" void kernel_launch(void* const* d_in, const int* in_sizes, int n_in,
                              void* d_out, int out_size, void* d_ws, size_t ws_size,
                              hipStream_t stream) {
  const float* x  = (const float*)d_in[0];
  // d_in[1] = top_k scalar (=2), compile-time fixed
  const float* Wg = (const float*)d_in[2];
  const float* bg = (const float*)d_in[3];
  const float* W1 = (const float*)d_in[4];
  const float* b1 = (const float*)d_in[5];
  const float* W2 = (const float*)d_in[6];
  const float* b2 = (const float*)d_in[7];
  float* out = (float*)d_out;

  char* p = (char*)d_ws;
  auto take = [&](size_t bytes) {
    char* q = p;
    p += (bytes + 255) & ~(size_t)255;
    return q;
  };
  int*   offs       = (int*)take(64);
  int*   blockcnt   = (int*)take((size_t)NB * 8 * sizeof(int));
  int*   blockstart = (int*)take((size_t)NB * 8 * sizeof(int));
  int*   panelE     = (int*)take(1024);
  int*   panelB     = (int*)take(1024);
  int*   nPanels    = (int*)take(256);
  int*   topki      = (int*)take((size_t)Tn * 2 * sizeof(int));
  float* topkw      = (float*)take((size_t)Tn * 2 * sizeof(float));
  int*   rows       = (int*)take((size_t)Tn * 2 * sizeof(int));
  int*   slotmap    = (int*)take((size_t)Tn * 2 * sizeof(int));
  u16*   xb         = (u16*)take((size_t)Tn * Dd * 2);
  u16*   w1t        = (u16*)take((size_t)Ee * Dd * Hh * 2);
  u16*   w2t        = (u16*)take((size_t)Ee * Dd * Hh * 2);
  u16*   hbuf       = (u16*)take((size_t)Tn * 2 * Hh * 2);
  u16*   ybuf       = (u16*)take((size_t)Tn * 2 * Dd * 2);

  transpose_cvt_kernel<<<dim3(Hh / 64, Dd / 64, Ee), dim3(64, 8), 0, stream>>>(W1, w1t, Dd, Hh);
  transpose_cvt_kernel<<<dim3(Dd / 64, Hh / 64, Ee), dim3(64, 8), 0, stream>>>(W2, w2t, Hh, Dd);
  gating_kernel<<<Tn / 4, 256, 0, stream>>>(x, Wg, bg, topki, topkw, xb);
  hist_kernel<<<NB, 256, 0, stream>>>(topki, blockcnt);
  prefix_kernel<<<1, 64, 0, stream>>>(blockcnt, offs, blockstart, panelE, panelB, nPanels);
  scatter_kernel<<<NB, 256, 0, stream>>>(topki, blockstart, rows, slotmap);
  gemm1_kernel<<<8 * 16 * MAXP, 256, 0, stream>>>(xb, w1t, b1, offs, rows,
                                                  panelE, panelB, nPanels, hbuf);
  gemm2_kernel<<<8 * 8 * MAXP, 256, 0, stream>>>(hbuf, w2t, b2, offs,
                                                 panelE, panelB, nPanels, ybuf);
  combine_kernel<<<(Tn * Dd / 8) / 256, 256, 0, stream>>>(ybuf, slotmap, topkw, out);
}

// Round 5
// 447.707 us; speedup vs baseline: 2.8007x; 1.0614x over previous
//
#include <hip/hip_runtime.h>

typedef unsigned short u16;
typedef short v8s __attribute__((ext_vector_type(8)));
typedef float v4f __attribute__((ext_vector_type(4)));

constexpr int Tn = 8192;   // tokens = B*S
constexpr int Dd = 1024;   // model dim
constexpr int Hh = 2048;   // hidden dim
constexpr int Ee = 8;      // experts
constexpr int NB = 32;     // histogram/scatter blocks
constexpr int MAXP = 17;   // ceil(max panels / 8)

// round-to-nearest-even f32 -> bf16 (inputs finite)
static __device__ __forceinline__ u16 f2bf(float v) {
  unsigned u = __float_as_uint(v);
  unsigned r = (u + 0x7fffu + ((u >> 16) & 1u)) >> 16;
  return (u16)r;
}

static __device__ __forceinline__ float bf2f(u16 v) {
  return __uint_as_float(((unsigned)v) << 16);
}

// async global -> LDS, 16B per lane; LDS dest = wave-uniform base + lane*16
static __device__ __forceinline__ void gload_lds16(const u16* g, u16* l) {
  __builtin_amdgcn_global_load_lds(
      (const __attribute__((address_space(1))) unsigned int*)g,
      (__attribute__((address_space(3))) unsigned int*)l, 16, 0, 0);
}

// in: fp32 [E][R][C]  ->  out: bf16 [E][C][R], 64x64 tiles
__global__ __launch_bounds__(512) void transpose_cvt_kernel(
    const float* __restrict__ in, u16* __restrict__ out, int R, int C) {
  __shared__ float tile[64][65];
  int e = blockIdx.z;
  const float* ip = in + (size_t)e * R * C;
  u16* op = out + (size_t)e * R * C;
  int c0 = blockIdx.x * 64, r0 = blockIdx.y * 64;
  int tx = threadIdx.x, ty = threadIdx.y;  // block (64,8)
  for (int i = ty; i < 64; i += 8)
    tile[i][tx] = ip[(size_t)(r0 + i) * C + c0 + tx];
  __syncthreads();
  for (int i = ty; i < 64; i += 8)
    op[(size_t)(c0 + i) * R + r0 + tx] = f2bf(tile[tx][i]);
}

// one wave per token; fused x->bf16 conversion; no global atomics
__global__ __launch_bounds__(256) void gating_kernel(
    const float* __restrict__ x, const float* __restrict__ Wg, const float* __restrict__ bg,
    int* __restrict__ topki, float* __restrict__ topkw, u16* __restrict__ xb) {
  int lane = threadIdx.x & 63;
  int t = blockIdx.x * 4 + (threadIdx.x >> 6);
  const float4* xr = reinterpret_cast<const float4*>(x + (size_t)t * Dd);
  float acc[8] = {0.f, 0.f, 0.f, 0.f, 0.f, 0.f, 0.f, 0.f};
#pragma unroll
  for (int it = 0; it < 4; ++it) {
    float4 xv = xr[it * 64 + lane];
    int r = it * 256 + lane * 4;
    ushort4 o;
    o.x = f2bf(xv.x); o.y = f2bf(xv.y); o.z = f2bf(xv.z); o.w = f2bf(xv.w);
    *reinterpret_cast<ushort4*>(xb + (size_t)t * Dd + r) = o;
    const float4* wr = reinterpret_cast<const float4*>(Wg + (size_t)r * 8);
    float xs[4] = {xv.x, xv.y, xv.z, xv.w};
#pragma unroll
    for (int q = 0; q < 4; ++q) {
      float4 a = wr[q * 2], b = wr[q * 2 + 1];
      acc[0] += xs[q] * a.x; acc[1] += xs[q] * a.y; acc[2] += xs[q] * a.z; acc[3] += xs[q] * a.w;
      acc[4] += xs[q] * b.x; acc[5] += xs[q] * b.y; acc[6] += xs[q] * b.z; acc[7] += xs[q] * b.w;
    }
  }
#pragma unroll
  for (int e = 0; e < 8; ++e) {
#pragma unroll
    for (int off = 32; off > 0; off >>= 1) acc[e] += __shfl_xor(acc[e], off, 64);
  }
  if (lane == 0) {
    float l[8];
    float mx = -1e30f;
#pragma unroll
    for (int e = 0; e < 8; ++e) { l[e] = acc[e] + bg[e]; mx = fmaxf(mx, l[e]); }
    int i0 = 0;
#pragma unroll
    for (int e = 1; e < 8; ++e) if (l[e] > l[i0]) i0 = e;
    int i1 = (i0 == 0) ? 1 : 0;
#pragma unroll
    for (int e = 0; e < 8; ++e) if (e != i0 && l[e] > l[i1]) i1 = e;
    float e0 = __expf(l[i0] - mx), e1 = __expf(l[i1] - mx);
    float inv = 1.0f / (e0 + e1);
    topki[2 * t] = i0; topki[2 * t + 1] = i1;
    topkw[2 * t] = e0 * inv; topkw[2 * t + 1] = e1 * inv;
  }
}

// per-block expert histogram via LDS atomics; 8 global stores per block
__global__ __launch_bounds__(256) void hist_kernel(const int* __restrict__ topki,
                                                   int* __restrict__ blockcnt) {
  __shared__ int bins[8];
  int tid = threadIdx.x, b = blockIdx.x;
  if (tid < 8) bins[tid] = 0;
  __syncthreads();
  atomicAdd(&bins[topki[b * 512 + tid]], 1);
  atomicAdd(&bins[topki[b * 512 + 256 + tid]], 1);
  __syncthreads();
  if (tid < 8) blockcnt[b * 8 + tid] = bins[tid];
}

// prefix sums + XCD-pinned panel work-list
__global__ void prefix_kernel(const int* __restrict__ blockcnt, int* __restrict__ offs,
                              int* __restrict__ blockstart,
                              int* __restrict__ panelE, int* __restrict__ panelB,
                              int* __restrict__ nPanels) {
  __shared__ int tmp[8][NB];
  __shared__ int tot[8];
  int tid = threadIdx.x;
  if (tid < 8) {
    int s = 0;
    for (int b = 0; b < NB; ++b) { tmp[tid][b] = s; s += blockcnt[b * 8 + tid]; }
    tot[tid] = s;
  }
  __syncthreads();
  if (tid == 0) {
    int o = 0;
    for (int e = 0; e < 8; ++e) { offs[e] = o; o += tot[e]; }
    offs[8] = o;
    int np = 0;
    for (int e = 0; e < 8; ++e) {
      for (int m0 = 0; m0 < tot[e]; m0 += 128) {
        panelE[np] = e;
        panelB[np] = offs[e] + m0;
        ++np;
      }
    }
    *nPanels = np;
  }
  __syncthreads();
  if (tid < 8)
    for (int b = 0; b < NB; ++b) blockstart[b * 8 + tid] = offs[tid] + tmp[tid][b];
}

// slot assignment with LDS-local ranks; zero global atomics
__global__ __launch_bounds__(256) void scatter_kernel(
    const int* __restrict__ topki, const int* __restrict__ blockstart,
    int* __restrict__ rows, int* __restrict__ slotmap) {
  __shared__ int lbins[8];
  int tid = threadIdx.x, b = blockIdx.x;
  if (tid < 8) lbins[tid] = blockstart[b * 8 + tid];
  __syncthreads();
#pragma unroll
  for (int j = 0; j < 2; ++j) {
    int idx = b * 512 + j * 256 + tid;
    int e = topki[idx];
    int slot = atomicAdd(&lbins[e], 1);
    rows[slot] = idx >> 1;
    slotmap[idx] = slot;
  }
}

// ---- GEMM cores: 128x128 tile, BK=64, XOR-swizzled LDS (2-way max conflicts) ----
// Staging: lane l of chunk stages global k-chunk g=(l&7)^((l>>3)&7) at LDS pos l&7.
// Row R stores logical chunk c at position c^(R&7); reads XOR the same mask.

// GEMM1: h[slot][n] = gelu( x[rows[slot]] @ W1[e] + b1[e] )
__global__ __launch_bounds__(256, 2) void gemm1_kernel(
    const u16* __restrict__ xb, const u16* __restrict__ w1t, const float* __restrict__ b1,
    const int* __restrict__ offs, const int* __restrict__ rows,
    const int* __restrict__ panelE, const int* __restrict__ panelB,
    const int* __restrict__ nPanels, u16* __restrict__ hbuf) {
  const int bid = blockIdx.x;
  const int xcd = bid & 7;
  const int q = bid >> 3;
  const int n = q & 15;               // Hh/128 = 16 n-blocks
  const int pi = (q >> 4) * 8 + xcd;
  if (pi >= *nPanels) return;
  const int e = panelE[pi];
  const int sbase = panelB[pi];
  const int lim = offs[e + 1];
  const int n0 = n * 128;

  __shared__ u16 As[128 * 64];
  __shared__ u16 Bs[128 * 64];

  const int tid = threadIdx.x;
  const int lane = tid & 63;
  const int wid = tid >> 6;
  const int wm = (wid >> 1) * 64;
  const int wn = (wid & 1) * 64;
  const int l16 = lane & 15;
  const int quad = lane >> 4;
  const int swz8 = (l16 & 7) * 8;     // read-side XOR mask (elems)

  const u16* aga[4];
  const u16* bga[4];
  u16* alds[4];
  u16* blds[4];
#pragma unroll
  for (int j = 0; j < 4; ++j) {
    int chunk = wid * 4 + j;              // 0..15, covers rows [chunk*8, chunk*8+8)
    int rowl = chunk * 8 + (lane >> 3);
    int g = (lane & 7) ^ ((lane >> 3) & 7);
    int kcol = g * 8;
    int slot = sbase + rowl;
    if (slot >= lim) slot = sbase;
    aga[j] = xb + (size_t)rows[slot] * Dd + kcol;
    bga[j] = w1t + ((size_t)e * Hh + n0 + rowl) * Dd + kcol;
    alds[j] = As + chunk * 512;           // 512 u16 = 1KB per wave-instruction
    blds[j] = Bs + chunk * 512;
  }

  v4f acc[4][4];
#pragma unroll
  for (int i = 0; i < 4; ++i)
#pragma unroll
    for (int j = 0; j < 4; ++j) acc[i][j] = {0.f, 0.f, 0.f, 0.f};

  int rowAoff[4], rowBoff[4];
#pragma unroll
  for (int t_ = 0; t_ < 4; ++t_) {
    rowAoff[t_] = (wm + t_ * 16 + l16) * 64;
    rowBoff[t_] = (wn + t_ * 16 + l16) * 64;
  }

  for (int k0 = 0; k0 < Dd; k0 += 64) {
    __syncthreads();
#pragma unroll
    for (int j = 0; j < 4; ++j) gload_lds16(aga[j] + k0, alds[j]);
#pragma unroll
    for (int j = 0; j < 4; ++j) gload_lds16(bga[j] + k0, blds[j]);
    __syncthreads();

#pragma unroll
    for (int s = 0; s < 2; ++s) {
      int coff = ((s * 4 + quad) * 8) ^ swz8;
      v8s a[4], b[4];
#pragma unroll
      for (int mt = 0; mt < 4; ++mt)
        a[mt] = *reinterpret_cast<const v8s*>(&As[rowAoff[mt] + coff]);
#pragma unroll
      for (int nt = 0; nt < 4; ++nt)
        b[nt] = *reinterpret_cast<const v8s*>(&Bs[rowBoff[nt] + coff]);
#pragma unroll
      for (int mt = 0; mt < 4; ++mt)
#pragma unroll
        for (int nt = 0; nt < 4; ++nt)
          acc[mt][nt] = __builtin_amdgcn_mfma_f32_16x16x32_bf16(a[mt], b[nt], acc[mt][nt], 0, 0, 0);
    }
  }

  float b1v[4];
  int ng[4];
#pragma unroll
  for (int nt = 0; nt < 4; ++nt) {
    ng[nt] = n0 + wn + nt * 16 + l16;
    b1v[nt] = b1[(size_t)e * Hh + ng[nt]];
  }
#pragma unroll
  for (int mt = 0; mt < 4; ++mt) {
#pragma unroll
    for (int i = 0; i < 4; ++i) {
      int m = wm + mt * 16 + quad * 4 + i;
      if (sbase + m < lim) {
        size_t rowbase = (size_t)(sbase + m) * Hh;
#pragma unroll
        for (int nt = 0; nt < 4; ++nt) {
          float v = acc[mt][nt][i] + b1v[nt];
          float s = 1.0f / (1.0f + __expf(-1.5957691216057308f * (v + 0.044715f * v * v * v)));
          hbuf[rowbase + ng[nt]] = f2bf(v * s);
        }
      }
    }
  }
}

// GEMM2: ybuf[slot][n] = h[slot] @ W2[e] + b2[e]
__global__ __launch_bounds__(256, 2) void gemm2_kernel(
    const u16* __restrict__ hbuf, const u16* __restrict__ w2t, const float* __restrict__ b2,
    const int* __restrict__ offs,
    const int* __restrict__ panelE, const int* __restrict__ panelB,
    const int* __restrict__ nPanels, u16* __restrict__ ybuf) {
  const int bid = blockIdx.x;
  const int xcd = bid & 7;
  const int q = bid >> 3;
  const int n = q & 7;                // Dd/128 = 8 n-blocks
  const int pi = (q >> 3) * 8 + xcd;
  if (pi >= *nPanels) return;
  const int e = panelE[pi];
  const int sbase = panelB[pi];
  const int lim = offs[e + 1];
  const int n0 = n * 128;

  __shared__ u16 As[128 * 64];
  __shared__ u16 Bs[128 * 64];

  const int tid = threadIdx.x;
  const int lane = tid & 63;
  const int wid = tid >> 6;
  const int wm = (wid >> 1) * 64;
  const int wn = (wid & 1) * 64;
  const int l16 = lane & 15;
  const int quad = lane >> 4;
  const int swz8 = (l16 & 7) * 8;

  const u16* aga[4];
  const u16* bga[4];
  u16* alds[4];
  u16* blds[4];
#pragma unroll
  for (int j = 0; j < 4; ++j) {
    int chunk = wid * 4 + j;
    int rowl = chunk * 8 + (lane >> 3);
    int g = (lane & 7) ^ ((lane >> 3) & 7);
    int kcol = g * 8;
    int slot = sbase + rowl;
    if (slot >= lim) slot = sbase;
    aga[j] = hbuf + (size_t)slot * Hh + kcol;
    bga[j] = w2t + ((size_t)e * Dd + n0 + rowl) * Hh + kcol;
    alds[j] = As + chunk * 512;
    blds[j] = Bs + chunk * 512;
  }

  v4f acc[4][4];
#pragma unroll
  for (int i = 0; i < 4; ++i)
#pragma unroll
    for (int j = 0; j < 4; ++j) acc[i][j] = {0.f, 0.f, 0.f, 0.f};

  int rowAoff[4], rowBoff[4];
#pragma unroll
  for (int t_ = 0; t_ < 4; ++t_) {
    rowAoff[t_] = (wm + t_ * 16 + l16) * 64;
    rowBoff[t_] = (wn + t_ * 16 + l16) * 64;
  }

  for (int k0 = 0; k0 < Hh; k0 += 64) {
    __syncthreads();
#pragma unroll
    for (int j = 0; j < 4; ++j) gload_lds16(aga[j] + k0, alds[j]);
#pragma unroll
    for (int j = 0; j < 4; ++j) gload_lds16(bga[j] + k0, blds[j]);
    __syncthreads();

#pragma unroll
    for (int s = 0; s < 2; ++s) {
      int coff = ((s * 4 + quad) * 8) ^ swz8;
      v8s a[4], b[4];
#pragma unroll
      for (int mt = 0; mt < 4; ++mt)
        a[mt] = *reinterpret_cast<const v8s*>(&As[rowAoff[mt] + coff]);
#pragma unroll
      for (int nt = 0; nt < 4; ++nt)
        b[nt] = *reinterpret_cast<const v8s*>(&Bs[rowBoff[nt] + coff]);
#pragma unroll
      for (int mt = 0; mt < 4; ++mt)
#pragma unroll
        for (int nt = 0; nt < 4; ++nt)
          acc[mt][nt] = __builtin_amdgcn_mfma_f32_16x16x32_bf16(a[mt], b[nt], acc[mt][nt], 0, 0, 0);
    }
  }

  float b2v[4];
  int ng[4];
#pragma unroll
  for (int nt = 0; nt < 4; ++nt) {
    ng[nt] = n0 + wn + nt * 16 + l16;
    b2v[nt] = b2[(size_t)e * Dd + ng[nt]];
  }
#pragma unroll
  for (int mt = 0; mt < 4; ++mt) {
#pragma unroll
    for (int i = 0; i < 4; ++i) {
      int m = wm + mt * 16 + quad * 4 + i;
      if (sbase + m < lim) {
        size_t rowbase = (size_t)(sbase + m) * Dd;
#pragma unroll
        for (int nt = 0; nt < 4; ++nt)
          ybuf[rowbase + ng[nt]] = f2bf(acc[mt][nt][i] + b2v[nt]);
      }
    }
  }
}

// out[t] = w0 * y[slot0] + w1 * y[slot1]
__global__ __launch_bounds__(256) void combine_kernel(
    const u16* __restrict__ ybuf, const int* __restrict__ slotmap,
    const float* __restrict__ topkw, float* __restrict__ out) {
  int idx = blockIdx.x * 256 + threadIdx.x;
  int t = idx >> 7;
  int d0 = (idx & 127) * 8;
  int s0 = slotmap[2 * t], s1 = slotmap[2 * t + 1];
  float w0 = topkw[2 * t], w1 = topkw[2 * t + 1];
  uint4 ya = *reinterpret_cast<const uint4*>(ybuf + (size_t)s0 * Dd + d0);
  uint4 yb = *reinterpret_cast<const uint4*>(ybuf + (size_t)s1 * Dd + d0);
  float r[8];
  const unsigned* pa = &ya.x;
  const unsigned* pb = &yb.x;
#pragma unroll
  for (int j = 0; j < 4; ++j) {
    unsigned a = pa[j], b = pb[j];
    r[2 * j]     = w0 * bf2f((u16)(a & 0xffff)) + w1 * bf2f((u16)(b & 0xffff));
    r[2 * j + 1] = w0 * bf2f((u16)(a >> 16))    + w1 * bf2f((u16)(b >> 16));
  }
  float4* op = reinterpret_cast<float4*>(out + (size_t)t * Dd + d0);
  op[0] = make_float4(r[0], r[1], r[2], r[3]);
  op[1] = make_float4(r[4], r[5], r[6], r[7]);
}

extern "C" void kernel_launch(void* const* d_in, const int* in_sizes, int n_in,
                              void* d_out, int out_size, void* d_ws, size_t ws_size,
                              hipStream_t stream) {
  const float* x  = (const float*)d_in[0];
  const float* Wg = (const float*)d_in[2];
  const float* bg = (const float*)d_in[3];
  const float* W1 = (const float*)d_in[4];
  const float* b1 = (const float*)d_in[5];
  const float* W2 = (const float*)d_in[6];
  const float* b2 = (const float*)d_in[7];
  float* out = (float*)d_out;

  char* p = (char*)d_ws;
  auto take = [&](size_t bytes) {
    char* q = p;
    p += (bytes + 255) & ~(size_t)255;
    return q;
  };
  int*   offs       = (int*)take(64);
  int*   blockcnt   = (int*)take((size_t)NB * 8 * sizeof(int));
  int*   blockstart = (int*)take((size_t)NB * 8 * sizeof(int));
  int*   panelE     = (int*)take(1024);
  int*   panelB     = (int*)take(1024);
  int*   nPanels    = (int*)take(256);
  int*   topki      = (int*)take((size_t)Tn * 2 * sizeof(int));
  float* topkw      = (float*)take((size_t)Tn * 2 * sizeof(float));
  int*   rows       = (int*)take((size_t)Tn * 2 * sizeof(int));
  int*   slotmap    = (int*)take((size_t)Tn * 2 * sizeof(int));
  u16*   xb         = (u16*)take((size_t)Tn * Dd * 2);
  u16*   w1t        = (u16*)take((size_t)Ee * Dd * Hh * 2);
  u16*   w2t        = (u16*)take((size_t)Ee * Dd * Hh * 2);
  u16*   hbuf       = (u16*)take((size_t)Tn * 2 * Hh * 2);
  u16*   ybuf       = (u16*)take((size_t)Tn * 2 * Dd * 2);

  transpose_cvt_kernel<<<dim3(Hh / 64, Dd / 64, Ee), dim3(64, 8), 0, stream>>>(W1, w1t, Dd, Hh);
  transpose_cvt_kernel<<<dim3(Dd / 64, Hh / 64, Ee), dim3(64, 8), 0, stream>>>(W2, w2t, Hh, Dd);
  gating_kernel<<<Tn / 4, 256, 0, stream>>>(x, Wg, bg, topki, topkw, xb);
  hist_kernel<<<NB, 256, 0, stream>>>(topki, blockcnt);
  prefix_kernel<<<1, 64, 0, stream>>>(blockcnt, offs, blockstart, panelE, panelB, nPanels);
  scatter_kernel<<<NB, 256, 0, stream>>>(topki, blockstart, rows, slotmap);
  gemm1_kernel<<<8 * 16 * MAXP, 256, 0, stream>>>(xb, w1t, b1, offs, rows,
                                                  panelE, panelB, nPanels, hbuf);
  gemm2_kernel<<<8 * 8 * MAXP, 256, 0, stream>>>(hbuf, w2t, b2, offs,
                                                 panelE, panelB, nPanels, ybuf);
  combine_kernel<<<(Tn * Dd / 8) / 256, 256, 0, stream>>>(ybuf, slotmap, topkw, out);
}